// Round 1
// baseline (2128.312 us; speedup 1.0000x reference)
//
#include <hip/hip_runtime.h>
#include <math.h>

// Problem constants
#define B_  32
#define S_  576
#define F_  700
#define D_  16
#define KC  1024          // codebook size
#define M_  (B_*S_)       // 18432 rows (b,s)
#define SD  (S_*D_)       // 9216
#define SF  (S_*F_)       // 403200

// workspace layout (float offsets)
#define OFF_H1   0ull          // [18432,256]  4,718,592
#define OFF_H0C  4718592ull    // [9216,512]   4,718,592 (row-chunk buffer)
#define OFF_ZE   9437184ull    // [18432,16]     294,912
#define OFF_ZQT  9732096ull    // [9216,32]      294,912 (zf transposed: [k][b])
#define OFF_HD0  10027008ull   // [32,1024]       32,768 (pre-bias, atomic accum)
#define OFF_HD1T 10059776ull   // [512,32]        16,384 (transposed)
#define OFF_LOSS 10076160ull   // 1

// output layout (float offsets)
#define OUT_MEAN 12902400
#define OUT_LV   13197312
#define OUT_LOSS 13492224

// ---------------------------------------------------------------------------
// Generic fp32 tiled GEMM: C[M,N] = act(A[M,K] @ W[K,N] + bias[N])
// BM=BN=128, BK=8, 256 threads, 8x8 per thread. M%128==0, N%128==0 assumed.
// K arbitrary (guarded). A row stride K may be unaligned -> scalar A loads.
// ---------------------------------------------------------------------------
template<int RELU>
__global__ __launch_bounds__(256, 2) void gemm_bias_act(
    const float* __restrict__ A, const float* __restrict__ W,
    const float* __restrict__ bias, float* __restrict__ C,
    int N, int K) {
  __shared__ float As[8][128];
  __shared__ float Ws[8][128];
  const int tid = threadIdx.x;
  const int a_row = tid >> 1;
  const int a_seg = (tid & 1) << 2;
  const int w_kk  = tid >> 5;
  const int w_col = (tid & 31) << 2;
  const int tm = (tid & 15) << 3;
  const int tn = (tid >> 4) << 3;
  const float* Ab = A + (size_t)(blockIdx.x * 128) * K;
  const float* Wb = W + blockIdx.y * 128;
  float acc[8][8] = {};

  for (int k0 = 0; k0 < K; k0 += 8) {
    // stage A (scalar guarded loads; row stride K may be odd e.g. 700)
    {
      const float* ap = Ab + (size_t)a_row * K + k0 + a_seg;
      int krem = K - (k0 + a_seg);
      float a0 = (krem > 0) ? ap[0] : 0.f;
      float a1 = (krem > 1) ? ap[1] : 0.f;
      float a2 = (krem > 2) ? ap[2] : 0.f;
      float a3 = (krem > 3) ? ap[3] : 0.f;
      As[a_seg+0][a_row] = a0;
      As[a_seg+1][a_row] = a1;
      As[a_seg+2][a_row] = a2;
      As[a_seg+3][a_row] = a3;
    }
    // stage W (vector loads, N%4==0 so rows are 16B aligned)
    {
      float4 wv = {0.f,0.f,0.f,0.f};
      int wk = k0 + w_kk;
      if (wk < K) wv = *(const float4*)(Wb + (size_t)wk * N + w_col);
      *(float4*)&Ws[w_kk][w_col] = wv;
    }
    __syncthreads();
    #pragma unroll
    for (int kk = 0; kk < 8; ++kk) {
      float ar[8], br[8];
      *(float4*)&ar[0] = *(const float4*)&As[kk][tm];
      *(float4*)&ar[4] = *(const float4*)&As[kk][tm+4];
      *(float4*)&br[0] = *(const float4*)&Ws[kk][tn];
      *(float4*)&br[4] = *(const float4*)&Ws[kk][tn+4];
      #pragma unroll
      for (int i = 0; i < 8; ++i)
        #pragma unroll
        for (int j = 0; j < 8; ++j)
          acc[i][j] = fmaf(ar[i], br[j], acc[i][j]);
    }
    __syncthreads();
  }
  // epilogue
  #pragma unroll
  for (int i = 0; i < 8; ++i) {
    size_t row = (size_t)blockIdx.x * 128 + tm + i;
    float* cp = C + row * N + blockIdx.y * 128 + tn;
    const float* bp = bias + blockIdx.y * 128 + tn;
    #pragma unroll
    for (int j = 0; j < 8; ++j) {
      float v = acc[i][j] + bp[j];
      if (RELU) v = fmaxf(v, 0.f);
      cp[j] = v;
    }
  }
}

// ---------------------------------------------------------------------------
// enc2 (N=32) + split + reparameterize.
// block = 256 threads = 8 rows x 32 cols. grid = 18432/8 = 2304.
// ---------------------------------------------------------------------------
__global__ __launch_bounds__(256) void enc2_reparam(
    const float* __restrict__ h1, const float* __restrict__ ew2,
    const float* __restrict__ eb2, const float* __restrict__ eps,
    float* __restrict__ mean_out, float* __restrict__ lv_out,
    float* __restrict__ z_e) {
  __shared__ float hs[8][256];
  __shared__ float es[8][32];
  const int tid = threadIdx.x;
  const int r0 = blockIdx.x * 8;
  {
    int lr = tid >> 5, lc = (tid & 31) << 3;
    const float* src = h1 + (size_t)(r0 + lr) * 256 + lc;
    *(float4*)&hs[lr][lc]   = *(const float4*)src;
    *(float4*)&hs[lr][lc+4] = *(const float4*)(src + 4);
  }
  __syncthreads();
  const int r = tid >> 5, c = tid & 31;
  float sum = eb2[c];
  #pragma unroll 8
  for (int k = 0; k < 256; ++k)
    sum = fmaf(hs[r][k], ew2[k*32 + c], sum);
  es[r][c] = sum;
  __syncthreads();
  if (c < 16) {
    int row = r0 + r;
    float m  = es[r][c];
    float lv = es[r][c+16];
    mean_out[(size_t)row*16 + c] = m;
    lv_out[(size_t)row*16 + c]   = lv;
    z_e[(size_t)row*16 + c] = fmaf(expf(0.5f*lv), eps[(size_t)row*16 + c], m);
  }
}

// ---------------------------------------------------------------------------
// VQ: per row argmin over 1024 codes (D=16), gather z_q into transposed
// layout zqT[(s*16+d)*32 + b], accumulate vq_loss numerator.
// block = 256 = 4 waves; lane = row, wave = code-range; grid = 18432/64 = 288.
// Codebook read from global (wave-uniform broadcast addresses, L1/L2-resident).
// ---------------------------------------------------------------------------
__global__ __launch_bounds__(256) void vq_kernel(
    const float* __restrict__ z_e, const float* __restrict__ cb,
    float* __restrict__ zqT, float* __restrict__ loss_acc) {
  __shared__ float red_d[256];
  __shared__ int   red_i[256];
  const int tid = threadIdx.x;
  const int lane = tid & 63;
  const int wave = tid >> 6;
  const int row = blockIdx.x * 64 + lane;

  float z[16];
  {
    const float4* zp = (const float4*)(z_e + (size_t)row * 16);
    *(float4*)&z[0]  = zp[0];
    *(float4*)&z[4]  = zp[1];
    *(float4*)&z[8]  = zp[2];
    *(float4*)&z[12] = zp[3];
  }

  float dmin = 1e30f;
  int   imin = 0;
  const float4* cp = ((const float4*)cb) + (size_t)wave * 256 * 4;
  #pragma unroll 4
  for (int j = 0; j < 256; ++j) {
    float4 c0 = cp[0], c1 = cp[1], c2 = cp[2], c3 = cp[3];
    cp += 4;
    float d = 0.f, t;
    t = z[0]-c0.x;  d = fmaf(t,t,d);  t = z[1]-c0.y;  d = fmaf(t,t,d);
    t = z[2]-c0.z;  d = fmaf(t,t,d);  t = z[3]-c0.w;  d = fmaf(t,t,d);
    t = z[4]-c1.x;  d = fmaf(t,t,d);  t = z[5]-c1.y;  d = fmaf(t,t,d);
    t = z[6]-c1.z;  d = fmaf(t,t,d);  t = z[7]-c1.w;  d = fmaf(t,t,d);
    t = z[8]-c2.x;  d = fmaf(t,t,d);  t = z[9]-c2.y;  d = fmaf(t,t,d);
    t = z[10]-c2.z; d = fmaf(t,t,d);  t = z[11]-c2.w; d = fmaf(t,t,d);
    t = z[12]-c3.x; d = fmaf(t,t,d);  t = z[13]-c3.y; d = fmaf(t,t,d);
    t = z[14]-c3.z; d = fmaf(t,t,d);  t = z[15]-c3.w; d = fmaf(t,t,d);
    int c = wave * 256 + j;
    if (d < dmin) { dmin = d; imin = c; }
  }
  red_d[tid] = dmin;
  red_i[tid] = imin;
  __syncthreads();
  if (tid < 64) {
    #pragma unroll
    for (int w = 1; w < 4; ++w) {
      float d2 = red_d[w*64 + lane];
      int   i2 = red_i[w*64 + lane];
      if (d2 < dmin || (d2 == dmin && i2 < imin)) { dmin = d2; imin = i2; }
    }
    // gather z_q, write transposed, accumulate loss
    float ssum = 0.f;
    int b = row / S_, s = row - b * S_;
    float* zt = zqT + (size_t)s * 16 * 32 + b;
    const float* cq = cb + (size_t)imin * 16;
    #pragma unroll
    for (int e = 0; e < 16; ++e) {
      float q = cq[e];
      float diff = z[e] - q;
      ssum = fmaf(diff, diff, ssum);
      zt[e * 32] = q;
    }
    #pragma unroll
    for (int off = 32; off > 0; off >>= 1)
      ssum += __shfl_down(ssum, off, 64);
    if (lane == 0) atomicAdd(loss_acc, ssum);
  }
}

// ---------------------------------------------------------------------------
// dec0: hd0_pre[32,1024] += zf[32,9216] @ dw0[9216,1024]  (split-K + atomics)
// grid (4 n-tiles, 36 k-splits of 256). zqT is [k][m] so a k-tile stages
// contiguously into LDS; lanes broadcast-read the 32 m-values per k.
// ---------------------------------------------------------------------------
__global__ __launch_bounds__(256) void dec0_kernel(
    const float* __restrict__ zqT, const float* __restrict__ dw0,
    float* __restrict__ hd0_pre) {
  __shared__ float At[256 * 32];  // 32 KB
  const int tid = threadIdx.x;
  const int n  = blockIdx.x * 256 + tid;
  const int k0 = blockIdx.y * 256;
  {
    const float4* src = (const float4*)(zqT + (size_t)k0 * 32);
    float4* dst = (float4*)At;
    #pragma unroll
    for (int i = 0; i < 8; ++i) dst[tid + 256*i] = src[tid + 256*i];
  }
  __syncthreads();
  float acc[32] = {};
  const float* wp = dw0 + (size_t)k0 * 1024 + n;
  #pragma unroll 2
  for (int k = 0; k < 256; ++k) {
    float w = wp[(size_t)k * 1024];
    const float4* ap = (const float4*)&At[k * 32];
    #pragma unroll
    for (int mm = 0; mm < 8; ++mm) {
      float4 a = ap[mm];
      acc[mm*4+0] = fmaf(a.x, w, acc[mm*4+0]);
      acc[mm*4+1] = fmaf(a.y, w, acc[mm*4+1]);
      acc[mm*4+2] = fmaf(a.z, w, acc[mm*4+2]);
      acc[mm*4+3] = fmaf(a.w, w, acc[mm*4+3]);
    }
  }
  #pragma unroll
  for (int m = 0; m < 32; ++m)
    atomicAdd(&hd0_pre[m*1024 + n], acc[m]);
}

// ---------------------------------------------------------------------------
// dec1: hd1T[n*32+m] = relu( relu(hd0_pre+db0)[m,:] @ dw1[:,n] + db1[n] )
// grid (32 m, 2 n-tiles of 256)
// ---------------------------------------------------------------------------
__global__ __launch_bounds__(256) void dec1_kernel(
    const float* __restrict__ hd0_pre, const float* __restrict__ db0,
    const float* __restrict__ dw1, const float* __restrict__ db1,
    float* __restrict__ hd1T) {
  __shared__ float As[1024];
  const int tid = threadIdx.x;
  const int m = blockIdx.x;
  for (int i = tid; i < 1024; i += 256)
    As[i] = fmaxf(hd0_pre[m*1024 + i] + db0[i], 0.f);
  __syncthreads();
  const int n = blockIdx.y * 256 + tid;
  float acc = db1[n];
  #pragma unroll 4
  for (int k = 0; k < 1024; ++k)
    acc = fmaf(As[k], dw1[(size_t)k * 512 + n], acc);
  hd1T[n*32 + m] = fmaxf(acc, 0.f);
}

// ---------------------------------------------------------------------------
// dec2: out[32,403200] = softplus(hd1[32,512] @ dw2[512,403200] + db2)
// HBM-bound on dw2 (826 MB). hd1T (64 KB) fully staged in LDS; each thread
// owns 2 consecutive columns (float2 coalesced W loads), acc[32] rows.
// grid 788, 2 blocks/CU (64 KB LDS).
// ---------------------------------------------------------------------------
__global__ __launch_bounds__(256) void dec2_kernel(
    const float* __restrict__ hd1T, const float* __restrict__ dw2,
    const float* __restrict__ db2, float* __restrict__ out) {
  __shared__ float At[512 * 32];  // 64 KB
  const int tid = threadIdx.x;
  {
    const float4* src = (const float4*)hd1T;
    float4* dst = (float4*)At;
    #pragma unroll
    for (int i = 0; i < 16; ++i) dst[tid + 256*i] = src[tid + 256*i];
  }
  __syncthreads();
  const int n = blockIdx.x * 512 + tid * 2;
  if (n >= SF) return;
  float2 acc[32];
  #pragma unroll
  for (int m = 0; m < 32; ++m) { acc[m].x = 0.f; acc[m].y = 0.f; }
  const float* wp = dw2 + n;
  #pragma unroll 2
  for (int k = 0; k < 512; ++k) {
    float2 w = *(const float2*)(wp + (size_t)k * SF);
    const float4* ap = (const float4*)&At[k * 32];
    #pragma unroll
    for (int mm = 0; mm < 8; ++mm) {
      float4 a = ap[mm];
      acc[mm*4+0].x = fmaf(a.x, w.x, acc[mm*4+0].x);
      acc[mm*4+0].y = fmaf(a.x, w.y, acc[mm*4+0].y);
      acc[mm*4+1].x = fmaf(a.y, w.x, acc[mm*4+1].x);
      acc[mm*4+1].y = fmaf(a.y, w.y, acc[mm*4+1].y);
      acc[mm*4+2].x = fmaf(a.z, w.x, acc[mm*4+2].x);
      acc[mm*4+2].y = fmaf(a.z, w.y, acc[mm*4+2].y);
      acc[mm*4+3].x = fmaf(a.w, w.x, acc[mm*4+3].x);
      acc[mm*4+3].y = fmaf(a.w, w.y, acc[mm*4+3].y);
    }
  }
  float2 bb = *(const float2*)(db2 + n);
  #pragma unroll
  for (int m = 0; m < 32; ++m) {
    float x0 = acc[m].x + bb.x;
    float x1 = acc[m].y + bb.y;
    float2 o;
    o.x = fmaxf(x0, 0.f) + log1pf(expf(-fabsf(x0)));
    o.y = fmaxf(x1, 0.f) + log1pf(expf(-fabsf(x1)));
    *(float2*)(out + (size_t)m * SF + n) = o;
  }
}

__global__ void finalize_loss(const float* __restrict__ loss_acc,
                              float* __restrict__ out_loss) {
  *out_loss = *loss_acc * (1.f / 294912.f);
}

// ---------------------------------------------------------------------------
extern "C" void kernel_launch(void* const* d_in, const int* in_sizes, int n_in,
                              void* d_out, int out_size, void* d_ws, size_t ws_size,
                              hipStream_t stream) {
  const float* x   = (const float*)d_in[0];
  const float* eps = (const float*)d_in[1];
  const float* ew0 = (const float*)d_in[2];
  const float* eb0 = (const float*)d_in[3];
  const float* ew1 = (const float*)d_in[4];
  const float* eb1 = (const float*)d_in[5];
  const float* ew2 = (const float*)d_in[6];
  const float* eb2 = (const float*)d_in[7];
  const float* dw0 = (const float*)d_in[8];
  const float* db0 = (const float*)d_in[9];
  const float* dw1 = (const float*)d_in[10];
  const float* db1 = (const float*)d_in[11];
  const float* dw2 = (const float*)d_in[12];
  const float* db2 = (const float*)d_in[13];
  const float* cbk = (const float*)d_in[14];
  float* out = (float*)d_out;
  float* ws  = (float*)d_ws;

  float* h1   = ws + OFF_H1;
  float* h0c  = ws + OFF_H0C;
  float* ze   = ws + OFF_ZE;
  float* zqT  = ws + OFF_ZQT;
  float* hd0  = ws + OFF_HD0;
  float* hd1T = ws + OFF_HD1T;
  float* lac  = ws + OFF_LOSS;

  hipMemsetAsync(hd0, 0, 32768 * sizeof(float), stream);
  hipMemsetAsync(lac, 0, sizeof(float), stream);

  // encoder in 2 row-chunks of 9216 (bounds peak ws at ~40 MB)
  for (int c = 0; c < 2; ++c) {
    const float* xa = x + (size_t)c * 9216 * F_;
    float* h1c = h1 + (size_t)c * 9216 * 256;
    gemm_bias_act<1><<<dim3(72, 4), 256, 0, stream>>>(xa, ew0, eb0, h0c, 512, 700);
    gemm_bias_act<1><<<dim3(72, 2), 256, 0, stream>>>(h0c, ew1, eb1, h1c, 256, 512);
  }
  enc2_reparam<<<2304, 256, 0, stream>>>(h1, ew2, eb2, eps,
                                         out + OUT_MEAN, out + OUT_LV, ze);
  vq_kernel<<<288, 256, 0, stream>>>(ze, cbk, zqT, lac);
  dec0_kernel<<<dim3(4, 36), 256, 0, stream>>>(zqT, dw0, hd0);
  dec1_kernel<<<dim3(32, 2), 256, 0, stream>>>(hd0, db0, dw1, db1, hd1T);
  dec2_kernel<<<788, 256, 0, stream>>>(hd1T, dw2, db2, out);
  finalize_loss<<<1, 1, 0, stream>>>(lac, out + OUT_LOSS);
}

// Round 2
// 1706.667 us; speedup vs baseline: 1.2471x; 1.2471x over previous
//
#include <hip/hip_runtime.h>
#include <math.h>

// Problem constants
#define B_  32
#define S_  576
#define F_  700
#define D_  16
#define KC  1024          // codebook size
#define M_  (B_*S_)       // 18432 rows (b,s)
#define SD  (S_*D_)       // 9216
#define SF  (S_*F_)       // 403200

// workspace layout (float offsets)
#define OFF_H0   0ull           // [18432,512]  9,437,184
#define OFF_H1   9437184ull     // [18432,256]  4,718,592
#define OFF_ZE   14155776ull    // [18432,16]     294,912
#define OFF_ZQT  14450688ull    // [9216,32]      294,912 (zf transposed: [k][b])
#define OFF_HD0  14745600ull    // [32,1024]       32,768
#define OFF_HD1T 14778368ull    // [512,32]        16,384
#define OFF_LOSS 14794752ull    // 1 (padded to 64)
#define OFF_WT   14794816ull    // bf16 weight buffers start here (as ushort*)
// ushort offsets within WT region:
#define WT_EH0   0ull           // ewh0T [512][704] = 360,448
#define WT_EL0   360448ull
#define WT_EH1   720896ull      // ewh1T [256][512] = 131,072
#define WT_EL1   851968ull      // total 983,040 ushort = 1.97 MB

// output layout (float offsets)
#define OUT_MEAN 12902400
#define OUT_LV   13197312
#define OUT_LOSS 13492224

typedef __attribute__((ext_vector_type(8))) short short8;
typedef __attribute__((ext_vector_type(4))) short short4v;
typedef __attribute__((ext_vector_type(4))) float floatx4;

__device__ __forceinline__ unsigned short f2bf(float f) {
  unsigned u = __float_as_uint(f);
  return (unsigned short)((u + 0x7FFFu + ((u >> 16) & 1u)) >> 16);
}
__device__ __forceinline__ float bf2f(unsigned short h) {
  return __uint_as_float((unsigned)h << 16);
}

// ---------------------------------------------------------------------------
// Weight prep: W[K][N] fp32 -> WhT/WlT [N][Kpad] bf16 hi/lo (zero-padded K).
// block 256 = 32x8, tile 32x32 via padded LDS.
// ---------------------------------------------------------------------------
__global__ void wprep(const float* __restrict__ W, unsigned short* __restrict__ WhT,
                      unsigned short* __restrict__ WlT, int K, int N, int Kpad) {
  __shared__ float t[32][33];
  const int n0 = blockIdx.x * 32, k0 = blockIdx.y * 32;
  const int tx = threadIdx.x & 31, ty = threadIdx.x >> 5;
  #pragma unroll
  for (int i = 0; i < 4; ++i) {
    int k = k0 + ty + i * 8;
    t[ty + i * 8][tx] = (k < K) ? W[(size_t)k * N + n0 + tx] : 0.f;
  }
  __syncthreads();
  #pragma unroll
  for (int i = 0; i < 4; ++i) {
    int n = ty + i * 8;
    float v = t[tx][n];
    unsigned short h = f2bf(v);
    unsigned short l = f2bf(v - bf2f(h));
    size_t o = (size_t)(n0 + n) * Kpad + k0 + tx;
    WhT[o] = h;
    WlT[o] = l;
  }
}

// ---------------------------------------------------------------------------
// Split-bf16 MFMA GEMM: C[M,N] = relu(A[M,K] @ W[K,N] + bias), fp32-accurate.
// A fp32 converted hi/lo during staging; W pre-transposed bf16 hi/lo [N][Kpad].
// Block 256 thr = 4 waves (2x2 over 128x128 tile), wave tile 64x64 = 4x4
// frags of 16x16x32 MFMA; per k-tile 3 products hh+hl+lh into one fp32 acc.
// LDS rows padded 32->40 bf16 (2-way banks = free).
// ---------------------------------------------------------------------------
__global__ __launch_bounds__(256) void mfma_gemm_relu(
    const float* __restrict__ A, const unsigned short* __restrict__ WhT,
    const unsigned short* __restrict__ WlT, const float* __restrict__ bias,
    float* __restrict__ C, int N, int K, int nkt) {
  __shared__ unsigned short Ah[128][40], Al[128][40];
  __shared__ unsigned short Bh[128][40], Bl[128][40];
  const int tid = threadIdx.x;
  const int n0 = blockIdx.x * 128, m0 = blockIdx.y * 128;
  const int srow = tid >> 3;         // 0..31
  const int skk  = (tid & 7) << 2;   // 0,4,...,28
  const int wid = tid >> 6, lane = tid & 63;
  const int q = lane >> 4, r16 = lane & 15;
  const int wm = (wid & 1) << 6, wn = (wid >> 1) << 6;
  const int Kp = nkt << 5;
  floatx4 acc[4][4] = {};

  for (int kt = 0; kt < nkt; ++kt) {
    const int k0 = kt << 5;
    #pragma unroll
    for (int p = 0; p < 4; ++p) {
      const int row = p * 32 + srow;
      // A: fp32 load + hi/lo split (K%4==0 so float4 never straddles the edge)
      float4 v = make_float4(0.f, 0.f, 0.f, 0.f);
      if (k0 + skk < K)
        v = *(const float4*)(A + (size_t)(m0 + row) * K + k0 + skk);
      unsigned short hx = f2bf(v.x), hy = f2bf(v.y), hz = f2bf(v.z), hw = f2bf(v.w);
      short4v hv = { (short)hx, (short)hy, (short)hz, (short)hw };
      short4v lv = { (short)f2bf(v.x - bf2f(hx)), (short)f2bf(v.y - bf2f(hy)),
                     (short)f2bf(v.z - bf2f(hz)), (short)f2bf(v.w - bf2f(hw)) };
      *(short4v*)&Ah[row][skk] = hv;
      *(short4v*)&Al[row][skk] = lv;
      // B: pre-split bf16, already padded to Kp
      size_t bo = (size_t)(n0 + row) * Kp + k0 + skk;
      *(short4v*)&Bh[row][skk] = *(const short4v*)(WhT + bo);
      *(short4v*)&Bl[row][skk] = *(const short4v*)(WlT + bo);
    }
    __syncthreads();
    short8 ah[4], al[4];
    #pragma unroll
    for (int mi = 0; mi < 4; ++mi) {
      ah[mi] = *(const short8*)&Ah[wm + mi * 16 + r16][q * 8];
      al[mi] = *(const short8*)&Al[wm + mi * 16 + r16][q * 8];
    }
    #pragma unroll
    for (int ni = 0; ni < 4; ++ni) {
      short8 bh = *(const short8*)&Bh[wn + ni * 16 + r16][q * 8];
      short8 bl = *(const short8*)&Bl[wn + ni * 16 + r16][q * 8];
      #pragma unroll
      for (int mi = 0; mi < 4; ++mi) {
        acc[mi][ni] = __builtin_amdgcn_mfma_f32_16x16x32_bf16(ah[mi], bh, acc[mi][ni], 0, 0, 0);
        acc[mi][ni] = __builtin_amdgcn_mfma_f32_16x16x32_bf16(ah[mi], bl, acc[mi][ni], 0, 0, 0);
        acc[mi][ni] = __builtin_amdgcn_mfma_f32_16x16x32_bf16(al[mi], bh, acc[mi][ni], 0, 0, 0);
      }
    }
    __syncthreads();
  }
  // epilogue: C/D layout col=lane&15, row=q*4+reg
  #pragma unroll
  for (int ni = 0; ni < 4; ++ni) {
    const int col = n0 + wn + ni * 16 + r16;
    const float bv = bias[col];
    #pragma unroll
    for (int mi = 0; mi < 4; ++mi) {
      const int row = m0 + wm + mi * 16 + q * 4;
      #pragma unroll
      for (int rg = 0; rg < 4; ++rg) {
        float val = acc[mi][ni][rg] + bv;
        C[(size_t)(row + rg) * N + col] = fmaxf(val, 0.f);
      }
    }
  }
}

// ---------------------------------------------------------------------------
// enc2 (N=32) + split + reparameterize.  grid = 18432/8 = 2304.
// ---------------------------------------------------------------------------
__global__ __launch_bounds__(256) void enc2_reparam(
    const float* __restrict__ h1, const float* __restrict__ ew2,
    const float* __restrict__ eb2, const float* __restrict__ eps,
    float* __restrict__ mean_out, float* __restrict__ lv_out,
    float* __restrict__ z_e) {
  __shared__ float hs[8][256];
  __shared__ float es[8][32];
  const int tid = threadIdx.x;
  const int r0 = blockIdx.x * 8;
  {
    int lr = tid >> 5, lc = (tid & 31) << 3;
    const float* src = h1 + (size_t)(r0 + lr) * 256 + lc;
    *(float4*)&hs[lr][lc]   = *(const float4*)src;
    *(float4*)&hs[lr][lc+4] = *(const float4*)(src + 4);
  }
  __syncthreads();
  const int r = tid >> 5, c = tid & 31;
  float sum = eb2[c];
  #pragma unroll 8
  for (int k = 0; k < 256; ++k)
    sum = fmaf(hs[r][k], ew2[k*32 + c], sum);
  es[r][c] = sum;
  __syncthreads();
  if (c < 16) {
    int row = r0 + r;
    float m  = es[r][c];
    float lv = es[r][c+16];
    mean_out[(size_t)row*16 + c] = m;
    lv_out[(size_t)row*16 + c]   = lv;
    z_e[(size_t)row*16 + c] = fmaf(expf(0.5f*lv), eps[(size_t)row*16 + c], m);
  }
}

// ---------------------------------------------------------------------------
// VQ: per row argmin over 1024 codes (D=16), gather z_q transposed, loss acc.
// ---------------------------------------------------------------------------
__global__ __launch_bounds__(256) void vq_kernel(
    const float* __restrict__ z_e, const float* __restrict__ cb,
    float* __restrict__ zqT, float* __restrict__ loss_acc) {
  __shared__ float red_d[256];
  __shared__ int   red_i[256];
  const int tid = threadIdx.x;
  const int lane = tid & 63;
  const int wave = tid >> 6;
  const int row = blockIdx.x * 64 + lane;

  float z[16];
  {
    const float4* zp = (const float4*)(z_e + (size_t)row * 16);
    *(float4*)&z[0]  = zp[0];
    *(float4*)&z[4]  = zp[1];
    *(float4*)&z[8]  = zp[2];
    *(float4*)&z[12] = zp[3];
  }

  float dmin = 1e30f;
  int   imin = 0;
  const float4* cp = ((const float4*)cb) + (size_t)wave * 256 * 4;
  #pragma unroll 4
  for (int j = 0; j < 256; ++j) {
    float4 c0 = cp[0], c1 = cp[1], c2 = cp[2], c3 = cp[3];
    cp += 4;
    float d = 0.f, t;
    t = z[0]-c0.x;  d = fmaf(t,t,d);  t = z[1]-c0.y;  d = fmaf(t,t,d);
    t = z[2]-c0.z;  d = fmaf(t,t,d);  t = z[3]-c0.w;  d = fmaf(t,t,d);
    t = z[4]-c1.x;  d = fmaf(t,t,d);  t = z[5]-c1.y;  d = fmaf(t,t,d);
    t = z[6]-c1.z;  d = fmaf(t,t,d);  t = z[7]-c1.w;  d = fmaf(t,t,d);
    t = z[8]-c2.x;  d = fmaf(t,t,d);  t = z[9]-c2.y;  d = fmaf(t,t,d);
    t = z[10]-c2.z; d = fmaf(t,t,d);  t = z[11]-c2.w; d = fmaf(t,t,d);
    t = z[12]-c3.x; d = fmaf(t,t,d);  t = z[13]-c3.y; d = fmaf(t,t,d);
    t = z[14]-c3.z; d = fmaf(t,t,d);  t = z[15]-c3.w; d = fmaf(t,t,d);
    int c = wave * 256 + j;
    if (d < dmin) { dmin = d; imin = c; }
  }
  red_d[tid] = dmin;
  red_i[tid] = imin;
  __syncthreads();
  if (tid < 64) {
    #pragma unroll
    for (int w = 1; w < 4; ++w) {
      float d2 = red_d[w*64 + lane];
      int   i2 = red_i[w*64 + lane];
      if (d2 < dmin || (d2 == dmin && i2 < imin)) { dmin = d2; imin = i2; }
    }
    float ssum = 0.f;
    int b = row / S_, s = row - b * S_;
    float* zt = zqT + (size_t)s * 16 * 32 + b;
    const float* cq = cb + (size_t)imin * 16;
    #pragma unroll
    for (int e = 0; e < 16; ++e) {
      float qv = cq[e];
      float diff = z[e] - qv;
      ssum = fmaf(diff, diff, ssum);
      zt[e * 32] = qv;
    }
    #pragma unroll
    for (int off = 32; off > 0; off >>= 1)
      ssum += __shfl_down(ssum, off, 64);
    if (lane == 0) atomicAdd(loss_acc, ssum);
  }
}

// ---------------------------------------------------------------------------
// dec0: hd0_pre[32,1024] += zf[32,9216] @ dw0[9216,1024]  (split-K + atomics)
// ---------------------------------------------------------------------------
__global__ __launch_bounds__(256) void dec0_kernel(
    const float* __restrict__ zqT, const float* __restrict__ dw0,
    float* __restrict__ hd0_pre) {
  __shared__ float At[256 * 32];
  const int tid = threadIdx.x;
  const int n  = blockIdx.x * 256 + tid;
  const int k0 = blockIdx.y * 256;
  {
    const float4* src = (const float4*)(zqT + (size_t)k0 * 32);
    float4* dst = (float4*)At;
    #pragma unroll
    for (int i = 0; i < 8; ++i) dst[tid + 256*i] = src[tid + 256*i];
  }
  __syncthreads();
  float acc[32] = {};
  const float* wp = dw0 + (size_t)k0 * 1024 + n;
  #pragma unroll 2
  for (int k = 0; k < 256; ++k) {
    float w = wp[(size_t)k * 1024];
    const float4* ap = (const float4*)&At[k * 32];
    #pragma unroll
    for (int mm = 0; mm < 8; ++mm) {
      float4 a = ap[mm];
      acc[mm*4+0] = fmaf(a.x, w, acc[mm*4+0]);
      acc[mm*4+1] = fmaf(a.y, w, acc[mm*4+1]);
      acc[mm*4+2] = fmaf(a.z, w, acc[mm*4+2]);
      acc[mm*4+3] = fmaf(a.w, w, acc[mm*4+3]);
    }
  }
  #pragma unroll
  for (int m = 0; m < 32; ++m)
    atomicAdd(&hd0_pre[m*1024 + n], acc[m]);
}

// ---------------------------------------------------------------------------
// dec1: hd1T[n*32+m] = relu( relu(hd0_pre+db0)[m,:] @ dw1[:,n] + db1[n] )
// ---------------------------------------------------------------------------
__global__ __launch_bounds__(256) void dec1_kernel(
    const float* __restrict__ hd0_pre, const float* __restrict__ db0,
    const float* __restrict__ dw1, const float* __restrict__ db1,
    float* __restrict__ hd1T) {
  __shared__ float As[1024];
  const int tid = threadIdx.x;
  const int m = blockIdx.x;
  for (int i = tid; i < 1024; i += 256)
    As[i] = fmaxf(hd0_pre[m*1024 + i] + db0[i], 0.f);
  __syncthreads();
  const int n = blockIdx.y * 256 + tid;
  float acc = db1[n];
  #pragma unroll 4
  for (int k = 0; k < 1024; ++k)
    acc = fmaf(As[k], dw1[(size_t)k * 512 + n], acc);
  hd1T[n*32 + m] = fmaxf(acc, 0.f);
}

// ---------------------------------------------------------------------------
// dec2: out[32,403200] = softplus(hd1[32,512] @ dw2[512,403200] + db2)
// ---------------------------------------------------------------------------
__global__ __launch_bounds__(256) void dec2_kernel(
    const float* __restrict__ hd1T, const float* __restrict__ dw2,
    const float* __restrict__ db2, float* __restrict__ out) {
  __shared__ float At[512 * 32];
  const int tid = threadIdx.x;
  {
    const float4* src = (const float4*)hd1T;
    float4* dst = (float4*)At;
    #pragma unroll
    for (int i = 0; i < 16; ++i) dst[tid + 256*i] = src[tid + 256*i];
  }
  __syncthreads();
  const int n = blockIdx.x * 512 + tid * 2;
  if (n >= SF) return;
  float2 acc[32];
  #pragma unroll
  for (int m = 0; m < 32; ++m) { acc[m].x = 0.f; acc[m].y = 0.f; }
  const float* wp = dw2 + n;
  #pragma unroll 2
  for (int k = 0; k < 512; ++k) {
    float2 w = *(const float2*)(wp + (size_t)k * SF);
    const float4* ap = (const float4*)&At[k * 32];
    #pragma unroll
    for (int mm = 0; mm < 8; ++mm) {
      float4 a = ap[mm];
      acc[mm*4+0].x = fmaf(a.x, w.x, acc[mm*4+0].x);
      acc[mm*4+0].y = fmaf(a.x, w.y, acc[mm*4+0].y);
      acc[mm*4+1].x = fmaf(a.y, w.x, acc[mm*4+1].x);
      acc[mm*4+1].y = fmaf(a.y, w.y, acc[mm*4+1].y);
      acc[mm*4+2].x = fmaf(a.z, w.x, acc[mm*4+2].x);
      acc[mm*4+2].y = fmaf(a.z, w.y, acc[mm*4+2].y);
      acc[mm*4+3].x = fmaf(a.w, w.x, acc[mm*4+3].x);
      acc[mm*4+3].y = fmaf(a.w, w.y, acc[mm*4+3].y);
    }
  }
  float2 bb = *(const float2*)(db2 + n);
  #pragma unroll
  for (int m = 0; m < 32; ++m) {
    float x0 = acc[m].x + bb.x;
    float x1 = acc[m].y + bb.y;
    float2 o;
    o.x = fmaxf(x0, 0.f) + log1pf(expf(-fabsf(x0)));
    o.y = fmaxf(x1, 0.f) + log1pf(expf(-fabsf(x1)));
    *(float2*)(out + (size_t)m * SF + n) = o;
  }
}

__global__ void finalize_loss(const float* __restrict__ loss_acc,
                              float* __restrict__ out_loss) {
  *out_loss = *loss_acc * (1.f / 294912.f);
}

// ---------------------------------------------------------------------------
extern "C" void kernel_launch(void* const* d_in, const int* in_sizes, int n_in,
                              void* d_out, int out_size, void* d_ws, size_t ws_size,
                              hipStream_t stream) {
  const float* x   = (const float*)d_in[0];
  const float* eps = (const float*)d_in[1];
  const float* ew0 = (const float*)d_in[2];
  const float* eb0 = (const float*)d_in[3];
  const float* ew1 = (const float*)d_in[4];
  const float* eb1 = (const float*)d_in[5];
  const float* ew2 = (const float*)d_in[6];
  const float* eb2 = (const float*)d_in[7];
  const float* dw0 = (const float*)d_in[8];
  const float* db0 = (const float*)d_in[9];
  const float* dw1 = (const float*)d_in[10];
  const float* db1 = (const float*)d_in[11];
  const float* dw2 = (const float*)d_in[12];
  const float* db2 = (const float*)d_in[13];
  const float* cbk = (const float*)d_in[14];
  float* out = (float*)d_out;
  float* ws  = (float*)d_ws;

  float* h0   = ws + OFF_H0;
  float* h1   = ws + OFF_H1;
  float* ze   = ws + OFF_ZE;
  float* zqT  = ws + OFF_ZQT;
  float* hd0  = ws + OFF_HD0;
  float* hd1T = ws + OFF_HD1T;
  float* lac  = ws + OFF_LOSS;
  unsigned short* wt = (unsigned short*)(ws + OFF_WT);
  unsigned short* ewh0T = wt + WT_EH0;
  unsigned short* ewl0T = wt + WT_EL0;
  unsigned short* ewh1T = wt + WT_EH1;
  unsigned short* ewl1T = wt + WT_EL1;

  hipMemsetAsync(hd0, 0, 32768 * sizeof(float), stream);
  hipMemsetAsync(lac, 0, sizeof(float), stream);

  // weight prep (bf16 hi/lo transposed, K zero-padded to x32)
  wprep<<<dim3(16, 22), 256, 0, stream>>>(ew0, ewh0T, ewl0T, 700, 512, 704);
  wprep<<<dim3(8, 16), 256, 0, stream>>>(ew1, ewh1T, ewl1T, 512, 256, 512);

  // encoder: split-bf16 MFMA GEMMs (fp32-accurate, no chunking)
  mfma_gemm_relu<<<dim3(4, 144), 256, 0, stream>>>(x,  ewh0T, ewl0T, eb0, h0, 512, 700, 22);
  mfma_gemm_relu<<<dim3(2, 144), 256, 0, stream>>>(h0, ewh1T, ewl1T, eb1, h1, 256, 512, 16);

  enc2_reparam<<<2304, 256, 0, stream>>>(h1, ew2, eb2, eps,
                                         out + OUT_MEAN, out + OUT_LV, ze);
  vq_kernel<<<288, 256, 0, stream>>>(ze, cbk, zqT, lac);
  dec0_kernel<<<dim3(4, 36), 256, 0, stream>>>(zqT, dw0, hd0);
  dec1_kernel<<<dim3(32, 2), 256, 0, stream>>>(hd0, db0, dw1, db1, hd1T);
  dec2_kernel<<<788, 256, 0, stream>>>(hd1T, dw2, db2, out);
  finalize_loss<<<1, 1, 0, stream>>>(lac, out + OUT_LOSS);
}

// Round 3
// 1664.624 us; speedup vs baseline: 1.2786x; 1.0253x over previous
//
#include <hip/hip_runtime.h>
#include <math.h>

// Problem constants
#define B_  32
#define S_  576
#define F_  700
#define D_  16
#define KC  1024          // codebook size
#define M_  (B_*S_)       // 18432 rows (b,s)
#define SD  (S_*D_)       // 9216
#define SF  (S_*F_)       // 403200

// workspace layout (float offsets)
#define OFF_H0   0ull           // [18432,512]
#define OFF_H1   9437184ull     // [18432,256]
#define OFF_ZE   14155776ull    // [18432,16]
#define OFF_ZQT  14450688ull    // [9216,32]  zf transposed [k][b]
#define OFF_HD0  14745600ull    // [1024,32]  hd0 TRANSPOSED [n][m], pre-bias
#define OFF_HD1T 14778368ull    // [512,32]   hd1 transposed [n][m], pre-bias
#define OFF_LOSS 14794752ull    // 1 (+pad)
#define OFF_WT   14794816ull    // bf16 weight buffers (as ushort*)
#define WT_EH0   0ull           // ewh0T [512][704]
#define WT_EL0   360448ull
#define WT_EH1   720896ull      // ewh1T [256][512]
#define WT_EL1   851968ull

// output layout (float offsets)
#define OUT_MEAN 12902400
#define OUT_LV   13197312
#define OUT_LOSS 13492224

typedef __attribute__((ext_vector_type(8))) short short8;
typedef __attribute__((ext_vector_type(4))) short short4v;
typedef __attribute__((ext_vector_type(4))) float floatx4;

__device__ __forceinline__ unsigned short f2bf(float f) {
  unsigned u = __float_as_uint(f);
  return (unsigned short)((u + 0x7FFFu + ((u >> 16) & 1u)) >> 16);
}
__device__ __forceinline__ float bf2f(unsigned short h) {
  return __uint_as_float((unsigned)h << 16);
}

// ---------------------------------------------------------------------------
// Weight prep: W[K][N] fp32 -> WhT/WlT [N][Kpad] bf16 hi/lo (zero-padded K).
// ---------------------------------------------------------------------------
__global__ void wprep(const float* __restrict__ W, unsigned short* __restrict__ WhT,
                      unsigned short* __restrict__ WlT, int K, int N, int Kpad) {
  __shared__ float t[32][33];
  const int n0 = blockIdx.x * 32, k0 = blockIdx.y * 32;
  const int tx = threadIdx.x & 31, ty = threadIdx.x >> 5;
  #pragma unroll
  for (int i = 0; i < 4; ++i) {
    int k = k0 + ty + i * 8;
    t[ty + i * 8][tx] = (k < K) ? W[(size_t)k * N + n0 + tx] : 0.f;
  }
  __syncthreads();
  #pragma unroll
  for (int i = 0; i < 4; ++i) {
    int n = ty + i * 8;
    float v = t[tx][n];
    unsigned short h = f2bf(v);
    unsigned short l = f2bf(v - bf2f(h));
    size_t o = (size_t)(n0 + n) * Kpad + k0 + tx;
    WhT[o] = h;
    WlT[o] = l;
  }
}

// ---------------------------------------------------------------------------
// Split-bf16 MFMA GEMM: C = relu(A @ W + bias), fp32-accurate (hh+hl+lh).
// ---------------------------------------------------------------------------
__global__ __launch_bounds__(256) void mfma_gemm_relu(
    const float* __restrict__ A, const unsigned short* __restrict__ WhT,
    const unsigned short* __restrict__ WlT, const float* __restrict__ bias,
    float* __restrict__ C, int N, int K, int nkt) {
  __shared__ unsigned short Ah[128][40], Al[128][40];
  __shared__ unsigned short Bh[128][40], Bl[128][40];
  const int tid = threadIdx.x;
  const int n0 = blockIdx.x * 128, m0 = blockIdx.y * 128;
  const int srow = tid >> 3;
  const int skk  = (tid & 7) << 2;
  const int wid = tid >> 6, lane = tid & 63;
  const int q = lane >> 4, r16 = lane & 15;
  const int wm = (wid & 1) << 6, wn = (wid >> 1) << 6;
  const int Kp = nkt << 5;
  floatx4 acc[4][4] = {};

  for (int kt = 0; kt < nkt; ++kt) {
    const int k0 = kt << 5;
    #pragma unroll
    for (int p = 0; p < 4; ++p) {
      const int row = p * 32 + srow;
      float4 v = make_float4(0.f, 0.f, 0.f, 0.f);
      if (k0 + skk < K)
        v = *(const float4*)(A + (size_t)(m0 + row) * K + k0 + skk);
      unsigned short hx = f2bf(v.x), hy = f2bf(v.y), hz = f2bf(v.z), hw = f2bf(v.w);
      short4v hv = { (short)hx, (short)hy, (short)hz, (short)hw };
      short4v lv = { (short)f2bf(v.x - bf2f(hx)), (short)f2bf(v.y - bf2f(hy)),
                     (short)f2bf(v.z - bf2f(hz)), (short)f2bf(v.w - bf2f(hw)) };
      *(short4v*)&Ah[row][skk] = hv;
      *(short4v*)&Al[row][skk] = lv;
      size_t bo = (size_t)(n0 + row) * Kp + k0 + skk;
      *(short4v*)&Bh[row][skk] = *(const short4v*)(WhT + bo);
      *(short4v*)&Bl[row][skk] = *(const short4v*)(WlT + bo);
    }
    __syncthreads();
    short8 ah[4], al[4];
    #pragma unroll
    for (int mi = 0; mi < 4; ++mi) {
      ah[mi] = *(const short8*)&Ah[wm + mi * 16 + r16][q * 8];
      al[mi] = *(const short8*)&Al[wm + mi * 16 + r16][q * 8];
    }
    #pragma unroll
    for (int ni = 0; ni < 4; ++ni) {
      short8 bh = *(const short8*)&Bh[wn + ni * 16 + r16][q * 8];
      short8 bl = *(const short8*)&Bl[wn + ni * 16 + r16][q * 8];
      #pragma unroll
      for (int mi = 0; mi < 4; ++mi) {
        acc[mi][ni] = __builtin_amdgcn_mfma_f32_16x16x32_bf16(ah[mi], bh, acc[mi][ni], 0, 0, 0);
        acc[mi][ni] = __builtin_amdgcn_mfma_f32_16x16x32_bf16(ah[mi], bl, acc[mi][ni], 0, 0, 0);
        acc[mi][ni] = __builtin_amdgcn_mfma_f32_16x16x32_bf16(al[mi], bh, acc[mi][ni], 0, 0, 0);
      }
    }
    __syncthreads();
  }
  #pragma unroll
  for (int ni = 0; ni < 4; ++ni) {
    const int col = n0 + wn + ni * 16 + r16;
    const float bv = bias[col];
    #pragma unroll
    for (int mi = 0; mi < 4; ++mi) {
      const int row = m0 + wm + mi * 16 + q * 4;
      #pragma unroll
      for (int rg = 0; rg < 4; ++rg) {
        float val = acc[mi][ni][rg] + bv;
        C[(size_t)(row + rg) * N + col] = fmaxf(val, 0.f);
      }
    }
  }
}

// ---------------------------------------------------------------------------
// enc2 (N=32) + split + reparameterize. ew2 (32 KB) staged in LDS.
// ---------------------------------------------------------------------------
__global__ __launch_bounds__(256) void enc2_reparam(
    const float* __restrict__ h1, const float* __restrict__ ew2,
    const float* __restrict__ eb2, const float* __restrict__ eps,
    float* __restrict__ mean_out, float* __restrict__ lv_out,
    float* __restrict__ z_e) {
  __shared__ float ws_[256 * 32];
  __shared__ float hs[8][256];
  __shared__ float es[8][32];
  const int tid = threadIdx.x;
  const int r0 = blockIdx.x * 8;
  {
    const float4* src = (const float4*)ew2;
    float4* dst = (float4*)ws_;
    #pragma unroll
    for (int i = 0; i < 8; ++i) dst[tid + 256 * i] = src[tid + 256 * i];
  }
  {
    int lr = tid >> 5, lc = (tid & 31) << 3;
    const float* src = h1 + (size_t)(r0 + lr) * 256 + lc;
    *(float4*)&hs[lr][lc]   = *(const float4*)src;
    *(float4*)&hs[lr][lc+4] = *(const float4*)(src + 4);
  }
  __syncthreads();
  const int r = tid >> 5, c = tid & 31;
  float sum = eb2[c];
  #pragma unroll 8
  for (int k = 0; k < 256; ++k)
    sum = fmaf(hs[r][k], ws_[k * 32 + c], sum);
  es[r][c] = sum;
  __syncthreads();
  if (c < 16) {
    int row = r0 + r;
    float m  = es[r][c];
    float lv = es[r][c+16];
    mean_out[(size_t)row*16 + c] = m;
    lv_out[(size_t)row*16 + c]   = lv;
    z_e[(size_t)row*16 + c] = fmaf(expf(0.5f*lv), eps[(size_t)row*16 + c], m);
  }
}

// ---------------------------------------------------------------------------
// VQ: 32 rows/block, 8 code-groups of 128. grid = 576.
// ---------------------------------------------------------------------------
__global__ __launch_bounds__(256) void vq_kernel(
    const float* __restrict__ z_e, const float* __restrict__ cb,
    float* __restrict__ zqT, float* __restrict__ loss_acc) {
  __shared__ float red_d[256];
  __shared__ int   red_i[256];
  const int tid = threadIdx.x;
  const int r = tid & 31;
  const int g = tid >> 5;
  const int row = blockIdx.x * 32 + r;

  float z[16];
  {
    const float4* zp = (const float4*)(z_e + (size_t)row * 16);
    *(float4*)&z[0]  = zp[0];
    *(float4*)&z[4]  = zp[1];
    *(float4*)&z[8]  = zp[2];
    *(float4*)&z[12] = zp[3];
  }

  float dmin = 1e30f;
  int   imin = g * 128;
  const float4* cp = ((const float4*)cb) + (size_t)g * 128 * 4;
  #pragma unroll 4
  for (int j = 0; j < 128; ++j) {
    float4 c0 = cp[0], c1 = cp[1], c2 = cp[2], c3 = cp[3];
    cp += 4;
    float d = 0.f, t;
    t = z[0]-c0.x;  d = fmaf(t,t,d);  t = z[1]-c0.y;  d = fmaf(t,t,d);
    t = z[2]-c0.z;  d = fmaf(t,t,d);  t = z[3]-c0.w;  d = fmaf(t,t,d);
    t = z[4]-c1.x;  d = fmaf(t,t,d);  t = z[5]-c1.y;  d = fmaf(t,t,d);
    t = z[6]-c1.z;  d = fmaf(t,t,d);  t = z[7]-c1.w;  d = fmaf(t,t,d);
    t = z[8]-c2.x;  d = fmaf(t,t,d);  t = z[9]-c2.y;  d = fmaf(t,t,d);
    t = z[10]-c2.z; d = fmaf(t,t,d);  t = z[11]-c2.w; d = fmaf(t,t,d);
    t = z[12]-c3.x; d = fmaf(t,t,d);  t = z[13]-c3.y; d = fmaf(t,t,d);
    t = z[14]-c3.z; d = fmaf(t,t,d);  t = z[15]-c3.w; d = fmaf(t,t,d);
    int c = g * 128 + j;
    if (d < dmin) { dmin = d; imin = c; }
  }
  red_d[tid] = dmin;
  red_i[tid] = imin;
  __syncthreads();
  if (tid < 32) {
    #pragma unroll
    for (int w = 1; w < 8; ++w) {
      float d2 = red_d[w*32 + tid];
      int   i2 = red_i[w*32 + tid];
      if (d2 < dmin) { dmin = d2; imin = i2; }   // ascending index order => strict <
    }
    float ssum = 0.f;
    int b = row / S_, s = row - b * S_;
    float* zt = zqT + (size_t)s * 16 * 32 + b;
    const float* cq = cb + (size_t)imin * 16;
    #pragma unroll
    for (int e = 0; e < 16; ++e) {
      float qv = cq[e];
      float diff = z[e] - qv;
      ssum = fmaf(diff, diff, ssum);
      zt[e * 32] = qv;
    }
    #pragma unroll
    for (int off = 16; off > 0; off >>= 1)
      ssum += __shfl_down(ssum, off, 64);
    if (tid == 0) atomicAdd(loss_acc, ssum);
  }
}

// ---------------------------------------------------------------------------
// dec0: hd0T_pre[n][m] += zf[32,9216] @ dw0[9216,1024]  (k-split 128, 8-deep
// pipelined loads, transposed atomic output)
// ---------------------------------------------------------------------------
__global__ __launch_bounds__(256) void dec0_kernel(
    const float* __restrict__ zqT, const float* __restrict__ dw0,
    float* __restrict__ hd0T_pre) {
  __shared__ float At[128 * 32];  // 16 KB
  const int tid = threadIdx.x;
  const int n  = blockIdx.x * 256 + tid;
  const int k0 = blockIdx.y * 128;
  {
    const float4* src = (const float4*)(zqT + (size_t)k0 * 32);
    float4* dst = (float4*)At;
    #pragma unroll
    for (int i = 0; i < 4; ++i) dst[tid + 256*i] = src[tid + 256*i];
  }
  __syncthreads();
  float acc[32] = {};
  const float* wp = dw0 + (size_t)k0 * 1024 + n;
  float w[8];
  #pragma unroll
  for (int j = 0; j < 8; ++j) w[j] = wp[(size_t)j * 1024];
  for (int kq = 0; kq < 128; kq += 8) {
    float nw[8];
    const bool more = (kq + 8) < 128;
    if (more) {
      #pragma unroll
      for (int j = 0; j < 8; ++j) nw[j] = wp[(size_t)(kq + 8 + j) * 1024];
    }
    #pragma unroll
    for (int j = 0; j < 8; ++j) {
      const float4* ap = (const float4*)&At[(kq + j) * 32];
      #pragma unroll
      for (int mm = 0; mm < 8; ++mm) {
        float4 a = ap[mm];
        acc[mm*4+0] = fmaf(a.x, w[j], acc[mm*4+0]);
        acc[mm*4+1] = fmaf(a.y, w[j], acc[mm*4+1]);
        acc[mm*4+2] = fmaf(a.z, w[j], acc[mm*4+2]);
        acc[mm*4+3] = fmaf(a.w, w[j], acc[mm*4+3]);
      }
    }
    if (more) {
      #pragma unroll
      for (int j = 0; j < 8; ++j) w[j] = nw[j];
    }
  }
  #pragma unroll
  for (int m = 0; m < 32; ++m)
    atomicAdd(&hd0T_pre[(size_t)n * 32 + m], acc[m]);
}

// ---------------------------------------------------------------------------
// dec1: hd1T_pre[n][m] += relu(hd0T_pre+db0) @ dw1.  grid (16 n-tiles, 16
// k-splits). Bias db1 deferred to dec2 staging.
// ---------------------------------------------------------------------------
__global__ __launch_bounds__(256) void dec1_kernel(
    const float* __restrict__ hd0T_pre, const float* __restrict__ db0,
    const float* __restrict__ dw1, float* __restrict__ hd1T_pre) {
  __shared__ float As[64 * 32];  // 8 KB, [kk][m]
  const int tid = threadIdx.x;
  const int n0 = blockIdx.x * 32, k0 = blockIdx.y * 64;
  #pragma unroll
  for (int i = 0; i < 2; ++i) {
    int idx4 = tid + 256 * i;
    int kk = idx4 >> 3;
    float4 v = ((const float4*)hd0T_pre)[k0 * 8 + idx4];
    float b = db0[k0 + kk];
    float4 o = { fmaxf(v.x + b, 0.f), fmaxf(v.y + b, 0.f),
                 fmaxf(v.z + b, 0.f), fmaxf(v.w + b, 0.f) };
    ((float4*)As)[idx4] = o;
  }
  __syncthreads();
  const int n = n0 + (tid & 31);
  const int mg = (tid >> 5) << 2;
  float acc[4] = {};
  const float* wp = dw1 + (size_t)k0 * 512 + n;
  #pragma unroll 4
  for (int kk = 0; kk < 64; ++kk) {
    float w = wp[(size_t)kk * 512];
    float4 a = *(const float4*)&As[kk * 32 + mg];
    acc[0] = fmaf(a.x, w, acc[0]);
    acc[1] = fmaf(a.y, w, acc[1]);
    acc[2] = fmaf(a.z, w, acc[2]);
    acc[3] = fmaf(a.w, w, acc[3]);
  }
  #pragma unroll
  for (int j = 0; j < 4; ++j)
    atomicAdd(&hd1T_pre[(size_t)n * 32 + mg + j], acc[j]);
}

// ---------------------------------------------------------------------------
// dec2: out = softplus(hd1 @ dw2 + db2). hd1 bias+relu fused into staging.
// 256 cols/block (grid 1575), 8-deep pipelined weight loads.
// ---------------------------------------------------------------------------
__global__ __launch_bounds__(256) void dec2_kernel(
    const float* __restrict__ hd1T_pre, const float* __restrict__ db1,
    const float* __restrict__ dw2, const float* __restrict__ db2,
    float* __restrict__ out) {
  __shared__ float At[512 * 32];  // 64 KB
  const int tid = threadIdx.x;
  #pragma unroll
  for (int i = 0; i < 16; ++i) {
    int idx4 = tid + 256 * i;
    int k = idx4 >> 3;
    float4 v = ((const float4*)hd1T_pre)[idx4];
    float b = db1[k];
    float4 o = { fmaxf(v.x + b, 0.f), fmaxf(v.y + b, 0.f),
                 fmaxf(v.z + b, 0.f), fmaxf(v.w + b, 0.f) };
    ((float4*)At)[idx4] = o;
  }
  __syncthreads();
  const int n = blockIdx.x * 256 + tid;
  float acc[32] = {};
  const float* wp = dw2 + n;
  float w[8];
  #pragma unroll
  for (int j = 0; j < 8; ++j) w[j] = wp[(size_t)j * SF];
  for (int k0 = 0; k0 < 512; k0 += 8) {
    float nw[8];
    const bool more = (k0 + 8) < 512;
    if (more) {
      #pragma unroll
      for (int j = 0; j < 8; ++j) nw[j] = wp[(size_t)(k0 + 8 + j) * SF];
    }
    #pragma unroll
    for (int j = 0; j < 8; ++j) {
      const float4* ap = (const float4*)&At[(k0 + j) * 32];
      #pragma unroll
      for (int mm = 0; mm < 8; ++mm) {
        float4 a = ap[mm];
        acc[mm*4+0] = fmaf(a.x, w[j], acc[mm*4+0]);
        acc[mm*4+1] = fmaf(a.y, w[j], acc[mm*4+1]);
        acc[mm*4+2] = fmaf(a.z, w[j], acc[mm*4+2]);
        acc[mm*4+3] = fmaf(a.w, w[j], acc[mm*4+3]);
      }
    }
    if (more) {
      #pragma unroll
      for (int j = 0; j < 8; ++j) w[j] = nw[j];
    }
  }
  const float bb = db2[n];
  #pragma unroll
  for (int m = 0; m < 32; ++m) {
    float xv = acc[m] + bb;
    out[(size_t)m * SF + n] = fmaxf(xv, 0.f) + log1pf(expf(-fabsf(xv)));
  }
}

__global__ void finalize_loss(const float* __restrict__ loss_acc,
                              float* __restrict__ out_loss) {
  *out_loss = *loss_acc * (1.f / 294912.f);
}

// ---------------------------------------------------------------------------
extern "C" void kernel_launch(void* const* d_in, const int* in_sizes, int n_in,
                              void* d_out, int out_size, void* d_ws, size_t ws_size,
                              hipStream_t stream) {
  const float* x   = (const float*)d_in[0];
  const float* eps = (const float*)d_in[1];
  const float* ew0 = (const float*)d_in[2];
  const float* eb0 = (const float*)d_in[3];
  const float* ew1 = (const float*)d_in[4];
  const float* eb1 = (const float*)d_in[5];
  const float* ew2 = (const float*)d_in[6];
  const float* eb2 = (const float*)d_in[7];
  const float* dw0 = (const float*)d_in[8];
  const float* db0 = (const float*)d_in[9];
  const float* dw1 = (const float*)d_in[10];
  const float* db1 = (const float*)d_in[11];
  const float* dw2 = (const float*)d_in[12];
  const float* db2 = (const float*)d_in[13];
  const float* cbk = (const float*)d_in[14];
  float* out = (float*)d_out;
  float* ws  = (float*)d_ws;

  float* h0    = ws + OFF_H0;
  float* h1    = ws + OFF_H1;
  float* ze    = ws + OFF_ZE;
  float* zqT   = ws + OFF_ZQT;
  float* hd0T  = ws + OFF_HD0;
  float* hd1T  = ws + OFF_HD1T;
  float* lac   = ws + OFF_LOSS;
  unsigned short* wt = (unsigned short*)(ws + OFF_WT);
  unsigned short* ewh0T = wt + WT_EH0;
  unsigned short* ewl0T = wt + WT_EL0;
  unsigned short* ewh1T = wt + WT_EH1;
  unsigned short* ewl1T = wt + WT_EL1;

  // single fused zero-init: hd0T (32768) | hd1T (16384) | loss (+pad 64)
  hipMemsetAsync(hd0T, 0, (32768 + 16384 + 64) * sizeof(float), stream);

  wprep<<<dim3(16, 22), 256, 0, stream>>>(ew0, ewh0T, ewl0T, 700, 512, 704);
  wprep<<<dim3(8, 16), 256, 0, stream>>>(ew1, ewh1T, ewl1T, 512, 256, 512);

  mfma_gemm_relu<<<dim3(4, 144), 256, 0, stream>>>(x,  ewh0T, ewl0T, eb0, h0, 512, 700, 22);
  mfma_gemm_relu<<<dim3(2, 144), 256, 0, stream>>>(h0, ewh1T, ewl1T, eb1, h1, 256, 512, 16);

  enc2_reparam<<<2304, 256, 0, stream>>>(h1, ew2, eb2, eps,
                                         out + OUT_MEAN, out + OUT_LV, ze);
  vq_kernel<<<576, 256, 0, stream>>>(ze, cbk, zqT, lac);
  dec0_kernel<<<dim3(4, 72), 256, 0, stream>>>(zqT, dw0, hd0T);
  dec1_kernel<<<dim3(16, 16), 256, 0, stream>>>(hd0T, db0, dw1, hd1T);
  dec2_kernel<<<1575, 256, 0, stream>>>(hd1T, db1, dw2, db2, out);
  finalize_loss<<<1, 1, 0, stream>>>(lac, out + OUT_LOSS);
}